// Round 1
// 503.542 us; speedup vs baseline: 1.0643x; 1.0643x over previous
//
#include <hip/hip_runtime.h>

typedef unsigned short u16;
typedef __bf16 bf16x8 __attribute__((ext_vector_type(8)));
typedef float f32x4 __attribute__((ext_vector_type(4)));

__device__ __forceinline__ u16 f2bf(float f) {
  unsigned int u = __builtin_bit_cast(unsigned int, f);
  u += 0x7fffu + ((u >> 16) & 1u);
  return (u16)(u >> 16);
}

// async global->LDS, 16B per lane. LDS dest is wave-uniform base + lane*16 (HW).
__device__ __forceinline__ void gload_lds16(const u16* g, u16* l) {
  __builtin_amdgcn_global_load_lds((const __attribute__((address_space(1))) unsigned int*)g,
                                   (__attribute__((address_space(3))) unsigned int*)l,
                                   16, 0, 0);
}

// ===== Fragment-major (FM) layout for 16x16x32 bf16 MFMA operands =====
// chunk (ri=r>>4, ki=k>>5) is 64 lanes x 16B, contiguous 1KB:
//   lane = (r&15) | (((k>>3)&3)<<4),  byte = (k&7)*2
//   u16 addr(r,k) = ((ri*KC + ki)*512) + lane*8 + (k&7)      [KC = K/32]

// ---------------- WT[j][c] = sum_s rmsw[s*1024+c] * Wdyn[(s*1024+c)*24 + j] ------------
__global__ __launch_bounds__(256) void weff_kernel(const float* __restrict__ rmsw,
                                                   const float* __restrict__ Wdyn,
                                                   float* __restrict__ WT) {
  int idx = blockIdx.x * 256 + threadIdx.x;  // 24576 threads
  int j = idx >> 10, c = idx & 1023;
  float s = 0.f;
#pragma unroll
  for (int st = 0; st < 4; ++st) {
    int r = st * 1024 + c;
    s += rmsw[r] * Wdyn[(long)r * 24 + j];
  }
  WT[idx] = s;
}

// ---------------- pack W (K x N fp32) -> FM bf16 of B^T (N rows, K cols) ----------------
__global__ __launch_bounds__(256) void pack_weight(const float* __restrict__ W,
                                                   u16* __restrict__ FMB,
                                                   const int N, const int KC) {
  const long gid = (long)blockIdx.x * 256 + threadIdx.x;  // N*K/8 threads
  const int n = (int)(gid % N);
  const int k0 = (int)(gid / N) * 8;
  unsigned int p[4];
#pragma unroll
  for (int d = 0; d < 4; ++d) {
    const float lo = W[(long)(k0 + 2 * d) * N + n];
    const float hi = W[(long)(k0 + 2 * d + 1) * N + n];
    p[d] = (unsigned)f2bf(lo) | ((unsigned)f2bf(hi) << 16);
  }
  const long ad = ((long)(n >> 4) * KC + (k0 >> 5)) * 512 +
                  ((n & 15) + (((k0 >> 3) & 3) << 4)) * 8;
  *(uint4*)(FMB + ad) = make_uint4(p[0], p[1], p[2], p[3]);
}

// ---------------- per-token prep: rms, dynamic(24), gates, sinkhorn, preA(FM) -----------
__global__ __launch_bounds__(256) void prep_tokens(
    const float* __restrict__ x, const float* __restrict__ WT,
    const float* __restrict__ bias_pre, const float* __restrict__ bias_post,
    const float* __restrict__ bias_res, const float* __restrict__ a_pre,
    const float* __restrict__ a_post, const float* __restrict__ a_res,
    u16* __restrict__ preA, float* __restrict__ scal) {
  const int t = blockIdx.x;
  const int tid = threadIdx.x;
  const float4 xv = *(const float4*)(x + (long)t * 1024 + tid * 4);
  float ssq = xv.x * xv.x + xv.y * xv.y + xv.z * xv.z + xv.w * xv.w;
  float raw[24];
#pragma unroll
  for (int j = 0; j < 24; ++j) {
    const float4 w = *(const float4*)(WT + (long)j * 1024 + tid * 4);
    raw[j] = xv.x * w.x + xv.y * w.y + xv.z * w.z + xv.w * w.w;
  }
#pragma unroll
  for (int m = 1; m < 64; m <<= 1) {
    ssq += __shfl_xor(ssq, m);
#pragma unroll
    for (int j = 0; j < 24; ++j) raw[j] += __shfl_xor(raw[j], m);
  }
  __shared__ float red[4][25];
  __shared__ float tot[25];
  const int lane = tid & 63, wv = tid >> 6;
  if (lane == 0) {
#pragma unroll
    for (int j = 0; j < 24; ++j) red[wv][j] = raw[j];
    red[wv][24] = ssq;
  }
  __syncthreads();
  if (tid < 25) tot[tid] = red[0][tid] + red[1][tid] + red[2][tid] + red[3][tid];
  __syncthreads();

  const float rms = sqrtf(tot[24] * (1.0f / 1024.0f) + 1e-8f);
  const float rinv = 1.0f / rms;

  const float ap = a_pre[0];
  float s_pre = 0.f;
#pragma unroll
  for (int i = 0; i < 4; ++i)
    s_pre += 1.f / (1.f + expf(-(ap * tot[i] * rinv + bias_pre[i])));

  unsigned int lo = (unsigned)f2bf(s_pre * xv.x) | ((unsigned)f2bf(s_pre * xv.y) << 16);
  unsigned int hi = (unsigned)f2bf(s_pre * xv.z) | ((unsigned)f2bf(s_pre * xv.w) << 16);
  const int c0 = tid * 4;
  const long pa = ((long)(t >> 4) * 32 + (c0 >> 5)) * 512 +
                  ((t & 15) + (((c0 >> 3) & 3) << 4)) * 8 + (c0 & 7);
  *(uint2*)(preA + pa) = make_uint2(lo, hi);

  if (tid < 16) {
    const float ar = a_res[0];
    float Mv = expf(ar * tot[8 + tid] * rinv + bias_res[tid]);
#pragma unroll
    for (int it = 0; it < 20; ++it) {
      float cs = Mv + __shfl_xor(Mv, 4);
      cs += __shfl_xor(cs, 8);
      Mv = Mv / (cs + 1e-8f);   // col normalize (axis=-2)
      float rs = Mv + __shfl_xor(Mv, 1);
      rs += __shfl_xor(rs, 2);
      Mv = Mv / (rs + 1e-8f);   // row normalize (axis=-1)
    }
    float rs = Mv + __shfl_xor(Mv, 1);
    rs += __shfl_xor(rs, 2);
    if ((tid & 3) == 0) scal[(long)t * 8 + (tid >> 2)] = rs;  // r_i
  }
  if (tid < 4) {
    const float apo = a_post[0];
    float hp = 2.f / (1.f + expf(-(apo * tot[4 + tid] * rinv + bias_post[tid])));
    scal[(long)t * 8 + 4 + tid] = hp;  // H_post
  }
}

// ---------------- LDS-staged bf16 MFMA GEMM (m97 structure), XCD-swizzled ---------------
// Flat 1D grid of 64*GX blocks.  c = b&7 (XCD via round-robin dispatch),
// x = (b>>3)%GX, y = c*8 + (b>>3)/GX.
// Block 128x128, 4 waves (2x2), wave tile 64x64 = 4x4 of 16x16x32 MFMA.
// K-loop: double-buffered LDS (2 x 16KB), staged with global_load_lds width=16.
// FM chunks are contiguous 1KB = exactly one global_load_lds_dwordx4 per wave.
// EPI: 0 = gelu -> bf16 FM dst (KCout)   [GEMM1 -> h]
//      1 = merged FM: r_s*x + hp_s*(f+bias)  [GEMM2, fused combine2]
//      2 = fp32 out = f + bias + x           [GEMM3, fused combine3]
template <int EPI>
__global__ __launch_bounds__(256, 4) void gemm_fm(const u16* __restrict__ A,
                                                  const u16* __restrict__ B,
                                                  const int KCtot, const int GX,
                                                  const int N, const int KCout,
                                                  const float* __restrict__ bias,
                                                  const float* __restrict__ X,
                                                  const float* __restrict__ scal,
                                                  void* __restrict__ dstv) {
  const int tid = threadIdx.x;
  const int lane = tid & 63;
  const int wave = tid >> 6;
  const int wm = wave >> 1, wn = wave & 1;
  const int b = blockIdx.x;
  const int c = b & 7;
  const int s = b >> 3;
  const int bx = s % GX;
  const int by = c * 8 + s / GX;

  // LDS: [buf][chunk 0-7 = A rows, 8-15 = B rows][1KB chunk]
  __shared__ u16 lds[2][16][512];

  // Each wave stages 4 chunks per K-step: t = wave*4 + l.
  const u16* gb[4];
  u16* lc[4];
#pragma unroll
  for (int l = 0; l < 4; ++l) {
    const int t = wave * 4 + l;
    gb[l] = (t < 8) ? (A + (long)(by * 8 + t) * KCtot * 512 + lane * 8)
                    : (B + (long)(bx * 8 + (t - 8)) * KCtot * 512 + lane * 8);
    lc[l] = &lds[0][t][0];
  }

#define STAGE(buf, kt)                                             \
  {                                                                \
    const long ko = (long)(kt)*512;                                \
    _Pragma("unroll") for (int l = 0; l < 4; ++l)                  \
        gload_lds16(gb[l] + ko, lc[l] + (buf)*8192);               \
  }

  f32x4 acc[4][4] = {};

  STAGE(0, 0);
  __syncthreads();  // drains vmcnt -> buf0 ready

  for (int kt = 0; kt < KCtot; ++kt) {
    const int cur = kt & 1;
    if (kt + 1 < KCtot) STAGE(cur ^ 1, kt + 1);
    bf16x8 af[4], bfr[4];
#pragma unroll
    for (int i = 0; i < 4; ++i) {
      af[i] = *(const bf16x8*)&lds[cur][wm * 4 + i][lane * 8];
      bfr[i] = *(const bf16x8*)&lds[cur][8 + wn * 4 + i][lane * 8];
    }
#pragma unroll
    for (int i = 0; i < 4; ++i)
#pragma unroll
      for (int j = 0; j < 4; ++j)
        acc[i][j] = __builtin_amdgcn_mfma_f32_16x16x32_bf16(af[i], bfr[j], acc[i][j], 0, 0, 0);
    // barrier: (a) all waves done reading lds[cur] before it is restaged next iter,
    //          (b) compiler-inserted vmcnt(0) drain completes staging of lds[cur^1].
    __syncthreads();
  }
#undef STAGE

  // Epilogue. C/D layout: col = lane&15, row = (lane>>4)*4 + reg  [verified m89/m91]
  if constexpr (EPI == 0) {
    u16* dst = (u16*)dstv;  // FM with KCout chunks (h feeds GEMM2 as A)
#pragma unroll
    for (int i = 0; i < 4; ++i)
#pragma unroll
      for (int r = 0; r < 4; ++r) {
        const int row = by * 128 + wm * 64 + i * 16 + (lane >> 4) * 4 + r;
#pragma unroll
        for (int j = 0; j < 4; ++j) {
          const int col = bx * 128 + wn * 64 + j * 16 + (lane & 15);
          float v = acc[i][j][r] + bias[col];
          float g = 0.5f * v * (1.0f + erff(v * 0.70710678118654752f));
          const long ad = ((long)(row >> 4) * KCout + (col >> 5)) * 512 +
                          ((row & 15) + (((col >> 3) & 3) << 4)) * 8 + (col & 7);
          dst[ad] = f2bf(g);
        }
      }
  } else if constexpr (EPI == 1) {
    u16* dst = (u16*)dstv;  // merged FM, KCout=128 chunks (k = s*1024 + col)
#pragma unroll
    for (int i = 0; i < 4; ++i)
#pragma unroll
      for (int r = 0; r < 4; ++r) {
        const int row = by * 128 + wm * 64 + i * 16 + (lane >> 4) * 4 + r;
        const float4 rv = *(const float4*)(scal + (long)row * 8);
        const float4 hv = *(const float4*)(scal + (long)row * 8 + 4);
        const float rr[4] = {rv.x, rv.y, rv.z, rv.w};
        const float hh[4] = {hv.x, hv.y, hv.z, hv.w};
#pragma unroll
        for (int j = 0; j < 4; ++j) {
          const int col = bx * 128 + wn * 64 + j * 16 + (lane & 15);
          const float f = acc[i][j][r] + bias[col];
          const float xval = X[(long)row * 1024 + col];
          const long base = ((long)(row >> 4) * 128 + (col >> 5)) * 512 +
                            ((row & 15) + (((col >> 3) & 3) << 4)) * 8 + (col & 7);
#pragma unroll
          for (int ss = 0; ss < 4; ++ss)
            dst[base + (long)ss * 32 * 512] = f2bf(rr[ss] * xval + hh[ss] * f);
        }
      }
  } else {
    float* dst = (float*)dstv;
#pragma unroll
    for (int i = 0; i < 4; ++i)
#pragma unroll
      for (int r = 0; r < 4; ++r) {
        const long row = by * 128 + wm * 64 + i * 16 + (lane >> 4) * 4 + r;
#pragma unroll
        for (int j = 0; j < 4; ++j) {
          const long col = bx * 128 + wn * 64 + j * 16 + (lane & 15);
          dst[row * 1024 + col] = acc[i][j][r] + bias[col] + X[row * 1024 + col];
        }
      }
  }
}

extern "C" void kernel_launch(void* const* d_in, const int* in_sizes, int n_in,
                              void* d_out, int out_size, void* d_ws, size_t ws_size,
                              hipStream_t stream) {
  (void)in_sizes; (void)n_in; (void)out_size; (void)ws_size;
  const float* x = (const float*)d_in[0];
  const float* rmsw = (const float*)d_in[1];
  const float* Wdyn = (const float*)d_in[2];
  const float* bias_pre = (const float*)d_in[3];
  const float* bias_post = (const float*)d_in[4];
  const float* bias_res = (const float*)d_in[5];
  const float* a_pre = (const float*)d_in[6];
  const float* a_post = (const float*)d_in[7];
  const float* a_res = (const float*)d_in[8];
  const float* W1 = (const float*)d_in[9];
  const float* b1 = (const float*)d_in[10];
  const float* W2 = (const float*)d_in[11];
  const float* b2 = (const float*)d_in[12];
  const float* Wout = (const float*)d_in[13];
  const float* bout = (const float*)d_in[14];
  float* out = (float*)d_out;
  char* ws = (char*)d_ws;

  // ws layout (MiB): [0,8) W1fm | [8,16) W2fm | [16,24) WOfm | [24,25) WT+scal
  //   [25,89)  h (bf16 FM, KCout=128)
  //   [89,153) merged (bf16 FM, KCout=128) -- initially ALIASED by preA (dead after GEMM1)
  constexpr size_t MB = 1048576;
  u16* W1fm = (u16*)(ws);
  u16* W2fm = (u16*)(ws + 8 * MB);
  u16* WOfm = (u16*)(ws + 16 * MB);
  float* WT = (float*)(ws + 24 * MB);
  float* scal = (float*)(ws + 24 * MB + 98304);
  u16* h = (u16*)(ws + 25 * MB);
  u16* merged = (u16*)(ws + 89 * MB);
  u16* preA = (u16*)(ws + 89 * MB);  // aliases merged (safe: preA dead before GEMM2)

  weff_kernel<<<96, 256, 0, stream>>>(rmsw, Wdyn, WT);
  pack_weight<<<2048, 256, 0, stream>>>(W1, W1fm, 4096, 32);    // K=1024 -> KC=32
  pack_weight<<<2048, 256, 0, stream>>>(W2, W2fm, 1024, 128);   // K=4096 -> KC=128
  pack_weight<<<2048, 256, 0, stream>>>(Wout, WOfm, 1024, 128);
  prep_tokens<<<8192, 256, 0, stream>>>(x, WT, bias_pre, bias_post, bias_res,
                                        a_pre, a_post, a_res, preA, scal);
  // GEMM1: h(FM) = gelu(preA @ W1 + b1)   M=8192 N=4096 K=1024; grid 8*8*GX, GX=32
  gemm_fm<0><<<2048, 256, 0, stream>>>(preA, W1fm, 32, 32, 4096, 128, b1, nullptr, nullptr, h);
  // GEMM2: merged(FM) = r*x + hp*(h @ W2 + b2)   M=8192 N=1024 K=4096; GX=8
  gemm_fm<1><<<512, 256, 0, stream>>>(h, W2fm, 128, 8, 1024, 128, b2, x, scal, merged);
  // GEMM3: out = merged @ Wout + bout + x        M=8192 N=1024 K=4096; GX=8
  gemm_fm<2><<<512, 256, 0, stream>>>(merged, WOfm, 128, 8, 1024, 0, bout, x, nullptr, out);
}

// Round 2
// 475.266 us; speedup vs baseline: 1.1276x; 1.0595x over previous
//
#include <hip/hip_runtime.h>

typedef unsigned short u16;
typedef __bf16 bf16x8 __attribute__((ext_vector_type(8)));
typedef float f32x4 __attribute__((ext_vector_type(4)));

__device__ __forceinline__ u16 f2bf(float f) {
  unsigned int u = __builtin_bit_cast(unsigned int, f);
  u += 0x7fffu + ((u >> 16) & 1u);
  return (u16)(u >> 16);
}

// async global->LDS, 16B per lane. LDS dest is wave-uniform base + lane*16 (HW).
__device__ __forceinline__ void gload_lds16(const u16* g, u16* l) {
  __builtin_amdgcn_global_load_lds((const __attribute__((address_space(1))) unsigned int*)g,
                                   (__attribute__((address_space(3))) unsigned int*)l,
                                   16, 0, 0);
}

// ===== Fragment-major (FM) layout for 16x16x32 bf16 MFMA operands =====
// chunk (ri=r>>4, ki=k>>5) is 64 lanes x 16B, contiguous 1KB:
//   lane = (r&15) | (((k>>3)&3)<<4),  byte = (k&7)*2
//   u16 addr(r,k) = ((ri*KC + ki)*512) + lane*8 + (k&7)      [KC = K/32]

// ---------------- WT[j][c] = sum_s rmsw[s*1024+c] * Wdyn[(s*1024+c)*24 + j] ------------
__global__ __launch_bounds__(256) void weff_kernel(const float* __restrict__ rmsw,
                                                   const float* __restrict__ Wdyn,
                                                   float* __restrict__ WT) {
  int idx = blockIdx.x * 256 + threadIdx.x;  // 24576 threads
  int j = idx >> 10, c = idx & 1023;
  float s = 0.f;
#pragma unroll
  for (int st = 0; st < 4; ++st) {
    int r = st * 1024 + c;
    s += rmsw[r] * Wdyn[(long)r * 24 + j];
  }
  WT[idx] = s;
}

// ---------------- pack W (K x N fp32) -> FM bf16 of B^T (N rows, K cols) ----------------
__global__ __launch_bounds__(256) void pack_weight(const float* __restrict__ W,
                                                   u16* __restrict__ FMB,
                                                   const int N, const int KC) {
  const long gid = (long)blockIdx.x * 256 + threadIdx.x;  // N*K/8 threads
  const int n = (int)(gid % N);
  const int k0 = (int)(gid / N) * 8;
  unsigned int p[4];
#pragma unroll
  for (int d = 0; d < 4; ++d) {
    const float lo = W[(long)(k0 + 2 * d) * N + n];
    const float hi = W[(long)(k0 + 2 * d + 1) * N + n];
    p[d] = (unsigned)f2bf(lo) | ((unsigned)f2bf(hi) << 16);
  }
  const long ad = ((long)(n >> 4) * KC + (k0 >> 5)) * 512 +
                  ((n & 15) + (((k0 >> 3) & 3) << 4)) * 8;
  *(uint4*)(FMB + ad) = make_uint4(p[0], p[1], p[2], p[3]);
}

// ---------------- per-token prep: rms, dynamic(24), gates, sinkhorn, preA(FM) -----------
__global__ __launch_bounds__(256) void prep_tokens(
    const float* __restrict__ x, const float* __restrict__ WT,
    const float* __restrict__ bias_pre, const float* __restrict__ bias_post,
    const float* __restrict__ bias_res, const float* __restrict__ a_pre,
    const float* __restrict__ a_post, const float* __restrict__ a_res,
    u16* __restrict__ preA, float* __restrict__ scal) {
  const int t = blockIdx.x;
  const int tid = threadIdx.x;
  const float4 xv = *(const float4*)(x + (long)t * 1024 + tid * 4);
  float ssq = xv.x * xv.x + xv.y * xv.y + xv.z * xv.z + xv.w * xv.w;
  float raw[24];
#pragma unroll
  for (int j = 0; j < 24; ++j) {
    const float4 w = *(const float4*)(WT + (long)j * 1024 + tid * 4);
    raw[j] = xv.x * w.x + xv.y * w.y + xv.z * w.z + xv.w * w.w;
  }
#pragma unroll
  for (int m = 1; m < 64; m <<= 1) {
    ssq += __shfl_xor(ssq, m);
#pragma unroll
    for (int j = 0; j < 24; ++j) raw[j] += __shfl_xor(raw[j], m);
  }
  __shared__ float red[4][25];
  __shared__ float tot[25];
  const int lane = tid & 63, wv = tid >> 6;
  if (lane == 0) {
#pragma unroll
    for (int j = 0; j < 24; ++j) red[wv][j] = raw[j];
    red[wv][24] = ssq;
  }
  __syncthreads();
  if (tid < 25) tot[tid] = red[0][tid] + red[1][tid] + red[2][tid] + red[3][tid];
  __syncthreads();

  const float rms = sqrtf(tot[24] * (1.0f / 1024.0f) + 1e-8f);
  const float rinv = 1.0f / rms;

  const float ap = a_pre[0];
  float s_pre = 0.f;
#pragma unroll
  for (int i = 0; i < 4; ++i)
    s_pre += 1.f / (1.f + expf(-(ap * tot[i] * rinv + bias_pre[i])));

  unsigned int lo = (unsigned)f2bf(s_pre * xv.x) | ((unsigned)f2bf(s_pre * xv.y) << 16);
  unsigned int hi = (unsigned)f2bf(s_pre * xv.z) | ((unsigned)f2bf(s_pre * xv.w) << 16);
  const int c0 = tid * 4;
  const long pa = ((long)(t >> 4) * 32 + (c0 >> 5)) * 512 +
                  ((t & 15) + (((c0 >> 3) & 3) << 4)) * 8 + (c0 & 7);
  *(uint2*)(preA + pa) = make_uint2(lo, hi);

  if (tid < 16) {
    const float ar = a_res[0];
    float Mv = expf(ar * tot[8 + tid] * rinv + bias_res[tid]);
#pragma unroll
    for (int it = 0; it < 20; ++it) {
      float cs = Mv + __shfl_xor(Mv, 4);
      cs += __shfl_xor(cs, 8);
      Mv = Mv / (cs + 1e-8f);   // col normalize (axis=-2)
      float rs = Mv + __shfl_xor(Mv, 1);
      rs += __shfl_xor(rs, 2);
      Mv = Mv / (rs + 1e-8f);   // row normalize (axis=-1)
    }
    float rs = Mv + __shfl_xor(Mv, 1);
    rs += __shfl_xor(rs, 2);
    if ((tid & 3) == 0) scal[(long)t * 8 + (tid >> 2)] = rs;  // r_i
  }
  if (tid < 4) {
    const float apo = a_post[0];
    float hp = 2.f / (1.f + expf(-(apo * tot[4 + tid] * rinv + bias_post[tid])));
    scal[(long)t * 8 + 4 + tid] = hp;  // H_post
  }
}

// ---------------- LDS-staged bf16 MFMA GEMM (m97 structure), XCD-swizzled ---------------
// Flat 1D grid of 64*GX blocks.  c = b&7 (XCD via round-robin dispatch),
// x = (b>>3)%GX, y = c*8 + (b>>3)/GX.
// Block 128x128, 4 waves (2x2), wave tile 64x64 = 4x4 of 16x16x32 MFMA.
// K-loop: double-buffered LDS (2 x 16KB), staged with global_load_lds width=16.
// Epilogue: output tile bounced through the (now dead) LDS staging buffer so that
// every global store is a fully-coalesced 1KB-per-wave dwordx4 (kills the 2.4x
// write amplification from scalar u16 FM stores seen in rocprof).
// EPI: 0 = gelu -> bf16 FM dst (KCout)   [GEMM1 -> h]
//      1 = merged FM: r_s*x + hp_s*(f+bias)  [GEMM2, fused combine2]
//      2 = fp32 out = f + bias + x           [GEMM3, fused combine3]
template <int EPI>
__global__ __launch_bounds__(256, 4) void gemm_fm(const u16* __restrict__ A,
                                                  const u16* __restrict__ B,
                                                  const int KCtot, const int GX,
                                                  const int N, const int KCout,
                                                  const float* __restrict__ bias,
                                                  const float* __restrict__ X,
                                                  const float* __restrict__ scal,
                                                  void* __restrict__ dstv) {
  const int tid = threadIdx.x;
  const int lane = tid & 63;
  const int wave = tid >> 6;
  const int wm = wave >> 1, wn = wave & 1;
  const int b = blockIdx.x;
  const int c = b & 7;
  const int s = b >> 3;
  const int bx = s % GX;
  const int by = c * 8 + s / GX;

  // LDS: [buf][chunk 0-7 = A rows, 8-15 = B rows][1KB chunk]
  __shared__ u16 lds[2][16][512];

  // Each wave stages 4 chunks per K-step: t = wave*4 + l.
  const u16* gb[4];
  u16* lc[4];
#pragma unroll
  for (int l = 0; l < 4; ++l) {
    const int t = wave * 4 + l;
    gb[l] = (t < 8) ? (A + (long)(by * 8 + t) * KCtot * 512 + lane * 8)
                    : (B + (long)(bx * 8 + (t - 8)) * KCtot * 512 + lane * 8);
    lc[l] = &lds[0][t][0];
  }

#define STAGE(buf, kt)                                             \
  {                                                                \
    const long ko = (long)(kt)*512;                                \
    _Pragma("unroll") for (int l = 0; l < 4; ++l)                  \
        gload_lds16(gb[l] + ko, lc[l] + (buf)*8192);               \
  }

  f32x4 acc[4][4] = {};

  STAGE(0, 0);
  __syncthreads();  // drains vmcnt -> buf0 ready

  for (int kt = 0; kt < KCtot; ++kt) {
    const int cur = kt & 1;
    if (kt + 1 < KCtot) STAGE(cur ^ 1, kt + 1);
    bf16x8 af[4], bfr[4];
#pragma unroll
    for (int i = 0; i < 4; ++i) {
      af[i] = *(const bf16x8*)&lds[cur][wm * 4 + i][lane * 8];
      bfr[i] = *(const bf16x8*)&lds[cur][8 + wn * 4 + i][lane * 8];
    }
#pragma unroll
    for (int i = 0; i < 4; ++i)
#pragma unroll
      for (int j = 0; j < 4; ++j)
        acc[i][j] = __builtin_amdgcn_mfma_f32_16x16x32_bf16(af[i], bfr[j], acc[i][j], 0, 0, 0);
    // barrier: (a) all waves done reading lds[cur] before it is restaged next iter,
    //          (b) compiler-inserted vmcnt(0) drain completes staging of lds[cur^1].
    __syncthreads();
  }
#undef STAGE

  // ---- Epilogue. C/D layout: col = lane&15, row = (lane>>4)*4 + reg [m89/m91] ----
  // Per-wave private 8KB LDS bounce region (K-loop buffer is dead past this point).
  u16* ep = ((u16*)lds) + wave * 4096;

  if constexpr (EPI == 0) {
    u16* dst = (u16*)dstv;  // FM with KCout chunks (h feeds GEMM2 as A)
#pragma unroll
    for (int i = 0; i < 4; ++i)
#pragma unroll
      for (int j = 0; j < 4; ++j) {
        const int col = bx * 128 + wn * 64 + j * 16 + (lane & 15);
        const float bcol = bias[col];
#pragma unroll
        for (int r = 0; r < 4; ++r) {
          const float v = acc[i][j][r] + bcol;
          const float g = 0.5f * v * (1.0f + erff(v * 0.70710678118654752f));
          // FM within-chunk: lane' = (row&15) | (((col>>3)&3)<<4), byte = col&7
          const int lp = ((lane >> 4) * 4 + r) | ((((j & 1) << 1) | ((lane & 15) >> 3)) << 4);
          ep[(i * 2 + (j >> 1)) * 512 + lp * 8 + (lane & 7)] = f2bf(g);
        }
      }
    __syncthreads();
#pragma unroll
    for (int ch = 0; ch < 8; ++ch) {
      const int i = ch >> 1, jc = ch & 1;
      const long row16 = by * 8 + wm * 4 + i;
      const long col32 = bx * 4 + wn * 2 + jc;
      *(uint4*)(dst + (row16 * KCout + col32) * 512 + lane * 8) =
          *(const uint4*)(ep + ch * 512 + lane * 8);
    }
  } else if constexpr (EPI == 1) {
    u16* dst = (u16*)dstv;  // merged FM, 128 chunks/rowgroup (k = ss*1024 + col)
#pragma unroll
    for (int i = 0; i < 4; ++i) {
      float rr[4][4], hh[4][4];  // [r][ss]
#pragma unroll
      for (int r = 0; r < 4; ++r) {
        const int row = by * 128 + wm * 64 + i * 16 + (lane >> 4) * 4 + r;
        const float4 rv = *(const float4*)(scal + (long)row * 8);
        const float4 hv = *(const float4*)(scal + (long)row * 8 + 4);
        rr[r][0] = rv.x; rr[r][1] = rv.y; rr[r][2] = rv.z; rr[r][3] = rv.w;
        hh[r][0] = hv.x; hh[r][1] = hv.y; hh[r][2] = hv.z; hh[r][3] = hv.w;
      }
#pragma unroll
      for (int jc = 0; jc < 2; ++jc) {
        __syncthreads();  // WAR: previous chunk-reads done before rewriting ep
#pragma unroll
        for (int jj = 0; jj < 2; ++jj) {
          const int j = jc * 2 + jj;
          const int col = bx * 128 + wn * 64 + j * 16 + (lane & 15);
          const float bcol = bias[col];
#pragma unroll
          for (int r = 0; r < 4; ++r) {
            const int row = by * 128 + wm * 64 + i * 16 + (lane >> 4) * 4 + r;
            const float f = acc[i][j][r] + bcol;
            const float xval = X[(long)row * 1024 + col];
            const int lp = ((lane >> 4) * 4 + r) | (((jj << 1) | ((lane & 15) >> 3)) << 4);
#pragma unroll
            for (int ss = 0; ss < 4; ++ss)
              ep[ss * 512 + lp * 8 + (lane & 7)] = f2bf(rr[r][ss] * xval + hh[r][ss] * f);
          }
        }
        __syncthreads();  // RAW: ep filled before coalesced read-back
        const long row16 = by * 8 + wm * 4 + i;
        const long col32 = bx * 4 + wn * 2 + jc;
#pragma unroll
        for (int ss = 0; ss < 4; ++ss)
          *(uint4*)(dst + (row16 * 128 + (long)ss * 32 + col32) * 512 + lane * 8) =
              *(const uint4*)(ep + ss * 512 + lane * 8);
      }
    }
  } else {
    float* dst = (float*)dstv;
    float* ep32 = (float*)ep;  // 2048 floats = 32 rows x 64 cols
#pragma unroll
    for (int half = 0; half < 2; ++half) {
      __syncthreads();  // WAR guard on ep32 reuse
#pragma unroll
      for (int i2 = 0; i2 < 2; ++i2) {
        const int i = half * 2 + i2;
#pragma unroll
        for (int j = 0; j < 4; ++j) {
          const int col = bx * 128 + wn * 64 + j * 16 + (lane & 15);
          const float bcol = bias[col];
#pragma unroll
          for (int r = 0; r < 4; ++r) {
            const long row = by * 128 + wm * 64 + i * 16 + (lane >> 4) * 4 + r;
            ep32[(i2 * 16 + (lane >> 4) * 4 + r) * 64 + j * 16 + (lane & 15)] =
                acc[i][j][r] + bcol + X[row * 1024 + col];
          }
        }
      }
      __syncthreads();  // RAW: ep32 filled
#pragma unroll
      for (int q = 0; q < 8; ++q) {
        const int lr = q * 4 + (lane >> 4);  // local row 0..31
        const long row = by * 128 + wm * 64 + half * 32 + lr;
        const long col = bx * 128 + wn * 64 + (lane & 15) * 4;
        *(float4*)(dst + row * 1024 + col) =
            *(const float4*)(ep32 + lr * 64 + (lane & 15) * 4);
      }
    }
  }
}

extern "C" void kernel_launch(void* const* d_in, const int* in_sizes, int n_in,
                              void* d_out, int out_size, void* d_ws, size_t ws_size,
                              hipStream_t stream) {
  (void)in_sizes; (void)n_in; (void)out_size; (void)ws_size;
  const float* x = (const float*)d_in[0];
  const float* rmsw = (const float*)d_in[1];
  const float* Wdyn = (const float*)d_in[2];
  const float* bias_pre = (const float*)d_in[3];
  const float* bias_post = (const float*)d_in[4];
  const float* bias_res = (const float*)d_in[5];
  const float* a_pre = (const float*)d_in[6];
  const float* a_post = (const float*)d_in[7];
  const float* a_res = (const float*)d_in[8];
  const float* W1 = (const float*)d_in[9];
  const float* b1 = (const float*)d_in[10];
  const float* W2 = (const float*)d_in[11];
  const float* b2 = (const float*)d_in[12];
  const float* Wout = (const float*)d_in[13];
  const float* bout = (const float*)d_in[14];
  float* out = (float*)d_out;
  char* ws = (char*)d_ws;

  // ws layout (MiB): [0,8) W1fm | [8,16) W2fm | [16,24) WOfm | [24,25) WT+scal
  //   [25,89)  h (bf16 FM, KCout=128)
  //   [89,153) merged (bf16 FM, KCout=128) -- initially ALIASED by preA (dead after GEMM1)
  constexpr size_t MB = 1048576;
  u16* W1fm = (u16*)(ws);
  u16* W2fm = (u16*)(ws + 8 * MB);
  u16* WOfm = (u16*)(ws + 16 * MB);
  float* WT = (float*)(ws + 24 * MB);
  float* scal = (float*)(ws + 24 * MB + 98304);
  u16* h = (u16*)(ws + 25 * MB);
  u16* merged = (u16*)(ws + 89 * MB);
  u16* preA = (u16*)(ws + 89 * MB);  // aliases merged (safe: preA dead before GEMM2)

  weff_kernel<<<96, 256, 0, stream>>>(rmsw, Wdyn, WT);
  pack_weight<<<2048, 256, 0, stream>>>(W1, W1fm, 4096, 32);    // K=1024 -> KC=32
  pack_weight<<<2048, 256, 0, stream>>>(W2, W2fm, 1024, 128);   // K=4096 -> KC=128
  pack_weight<<<2048, 256, 0, stream>>>(Wout, WOfm, 1024, 128);
  prep_tokens<<<8192, 256, 0, stream>>>(x, WT, bias_pre, bias_post, bias_res,
                                        a_pre, a_post, a_res, preA, scal);
  // GEMM1: h(FM) = gelu(preA @ W1 + b1)   M=8192 N=4096 K=1024; grid 8*8*GX, GX=32
  gemm_fm<0><<<2048, 256, 0, stream>>>(preA, W1fm, 32, 32, 4096, 128, b1, nullptr, nullptr, h);
  // GEMM2: merged(FM) = r*x + hp*(h @ W2 + b2)   M=8192 N=1024 K=4096; GX=8
  gemm_fm<1><<<512, 256, 0, stream>>>(h, W2fm, 128, 8, 1024, 128, b2, x, scal, merged);
  // GEMM3: out = merged @ Wout + bout + x        M=8192 N=1024 K=4096; GX=8
  gemm_fm<2><<<512, 256, 0, stream>>>(merged, WOfm, 128, 8, 1024, 0, bout, x, nullptr, out);
}

// Round 3
// 431.108 us; speedup vs baseline: 1.2431x; 1.1024x over previous
//
#include <hip/hip_runtime.h>

typedef unsigned short u16;
typedef __bf16 bf16x8 __attribute__((ext_vector_type(8)));
typedef float f32x4 __attribute__((ext_vector_type(4)));

__device__ __forceinline__ u16 f2bf(float f) {
  unsigned int u = __builtin_bit_cast(unsigned int, f);
  u += 0x7fffu + ((u >> 16) & 1u);
  return (u16)(u >> 16);
}

// async global->LDS, 16B per lane. LDS dest is wave-uniform base + lane*16 (HW).
__device__ __forceinline__ void gload_lds16(const u16* g, u16* l) {
  __builtin_amdgcn_global_load_lds((const __attribute__((address_space(1))) unsigned int*)g,
                                   (__attribute__((address_space(3))) unsigned int*)l,
                                   16, 0, 0);
}

// Branchless gelu with A&S 7.1.26 erf approx (|err|<=1.5e-7 abs, << bf16 rounding).
__device__ __forceinline__ float gelu_erf(float v) {
  const float z = v * 0.70710678118654752f;
  const float az = fabsf(z);
  const float t = __builtin_amdgcn_rcpf(1.0f + 0.3275911f * az);
  const float p = t * (0.254829592f +
                  t * (-0.284496736f +
                  t * (1.421413741f +
                  t * (-1.453152027f + t * 1.061405429f))));
  const float e = __expf(-az * az);
  float er = 1.0f - p * e;
  er = (z < 0.f) ? -er : er;
  return 0.5f * v * (1.0f + er);
}

// ===== Fragment-major (FM) layout for 16x16x32 bf16 MFMA operands =====
// chunk (ri=r>>4, ki=k>>5) is 64 lanes x 16B, contiguous 1KB:
//   lane = (r&15) | (((k>>3)&3)<<4),  byte = (k&7)*2
//   u16 addr(r,k) = ((ri*KC + ki)*512) + lane*8 + (k&7)      [KC = K/32]

// ---------------- WT[j][c] = sum_s rmsw[s*1024+c] * Wdyn[(s*1024+c)*24 + j] ------------
__global__ __launch_bounds__(256) void weff_kernel(const float* __restrict__ rmsw,
                                                   const float* __restrict__ Wdyn,
                                                   float* __restrict__ WT) {
  int idx = blockIdx.x * 256 + threadIdx.x;  // 24576 threads
  int j = idx >> 10, c = idx & 1023;
  float s = 0.f;
#pragma unroll
  for (int st = 0; st < 4; ++st) {
    int r = st * 1024 + c;
    s += rmsw[r] * Wdyn[(long)r * 24 + j];
  }
  WT[idx] = s;
}

// ---------------- pack all 3 weights (K x N fp32) -> FM bf16 of B^T in ONE dispatch ----
__global__ __launch_bounds__(256) void pack_all(const float* __restrict__ W1,
                                                const float* __restrict__ W2,
                                                const float* __restrict__ WO,
                                                u16* __restrict__ F1,
                                                u16* __restrict__ F2,
                                                u16* __restrict__ FO) {
  const int blk = blockIdx.x;
  const int sel = blk >> 11;  // 0,1,2 (2048 blocks each)
  const float* W;
  u16* FMB;
  int lgN, KC;
  if (sel == 0)      { W = W1; FMB = F1; lgN = 12; KC = 32; }
  else if (sel == 1) { W = W2; FMB = F2; lgN = 10; KC = 128; }
  else               { W = WO; FMB = FO; lgN = 10; KC = 128; }
  const long gid = (long)(blk & 2047) * 256 + threadIdx.x;  // N*K/8 threads
  const int N = 1 << lgN;
  const int n = (int)(gid & (N - 1));
  const int k0 = (int)(gid >> lgN) * 8;
  unsigned int p[4];
#pragma unroll
  for (int d = 0; d < 4; ++d) {
    const float lo = W[(long)(k0 + 2 * d) * N + n];
    const float hi = W[(long)(k0 + 2 * d + 1) * N + n];
    p[d] = (unsigned)f2bf(lo) | ((unsigned)f2bf(hi) << 16);
  }
  const long ad = ((long)(n >> 4) * KC + (k0 >> 5)) * 512 +
                  ((n & 15) + (((k0 >> 3) & 3) << 4)) * 8;
  *(uint4*)(FMB + ad) = make_uint4(p[0], p[1], p[2], p[3]);
}

// ---------------- per-token prep v2: 16 tokens/block, 512 threads ----------------------
// Fixes vs v1: WT L2 traffic /16 (token sharing), LDS tree replaces 150-shfl butterfly,
// preA written as COMPLETE FM chunks -> fully-coalesced uint4 stores (v1 scattered 8B
// pieces into chunks -> write amplification, same disease as the old GEMM epilogue).
__global__ __launch_bounds__(512) void prep_tokens(
    const float* __restrict__ x, const float* __restrict__ WT,
    const float* __restrict__ bias_pre, const float* __restrict__ bias_post,
    const float* __restrict__ bias_res, const float* __restrict__ a_pre,
    const float* __restrict__ a_post, const float* __restrict__ a_res,
    u16* __restrict__ preA, float* __restrict__ scal) {
  const int tid = threadIdx.x;
  const int b = blockIdx.x;          // 512 blocks, 16 tokens each
  const long t0 = (long)b * 16;

  __shared__ float red[32][16][26];  // [cc][tt][j] 53.2KB
  __shared__ float tot2[16][26];
  __shared__ float spre[16];

  // ---- phase 1: partial dots (thread = (tt = tid&15, cc = tid>>4), 32 c's each) ----
  {
    const int tt = tid & 15;
    const int cc = tid >> 4;  // 0..31
    const float* xp = x + (t0 + tt) * 1024 + cc * 32;
    float part[25];
#pragma unroll
    for (int j = 0; j < 25; ++j) part[j] = 0.f;
#pragma unroll
    for (int g = 0; g < 8; ++g) {
      const float4 xv = *(const float4*)(xp + g * 4);
      part[24] += xv.x * xv.x + xv.y * xv.y + xv.z * xv.z + xv.w * xv.w;
#pragma unroll
      for (int j = 0; j < 24; ++j) {
        const float4 wv = *(const float4*)(WT + (long)j * 1024 + cc * 32 + g * 4);
        part[j] += xv.x * wv.x + xv.y * wv.y + xv.z * wv.z + xv.w * wv.w;
      }
    }
#pragma unroll
    for (int j = 0; j < 25; ++j) red[cc][tt][j] = part[j];
  }
  __syncthreads();

  // ---- phase 2a: reduce over cc (thread = (tt = tid>>5, j = tid&31)) ----
  {
    const int tt = tid >> 5;
    const int j = tid & 31;
    if (j < 25) {
      float s = 0.f;
#pragma unroll
      for (int cc = 0; cc < 32; ++cc) s += red[cc][tt][j];
      tot2[tt][j] = s;
    }
  }
  __syncthreads();

  // ---- phase 2b: gates + sinkhorn (tid<256: thread = (tt = tid>>4, m = tid&15)) ----
  if (tid < 256) {
    const int tt = tid >> 4;
    const int m = tid & 15;
    const long t = t0 + tt;
    const float rms = sqrtf(tot2[tt][24] * (1.0f / 1024.0f) + 1e-8f);
    const float rinv = 1.0f / rms;

    if (m == 0) {
      const float ap = a_pre[0];
      float s_pre = 0.f;
#pragma unroll
      for (int i = 0; i < 4; ++i)
        s_pre += 1.f / (1.f + expf(-(ap * tot2[tt][i] * rinv + bias_pre[i])));
      spre[tt] = s_pre;
    }
    if (m < 4) {
      const float apo = a_post[0];
      float hp = 2.f / (1.f + expf(-(apo * tot2[tt][4 + m] * rinv + bias_post[m])));
      scal[t * 8 + 4 + m] = hp;  // H_post
    }
    const float ar = a_res[0];
    float Mv = expf(ar * tot2[tt][8 + m] * rinv + bias_res[m]);
#pragma unroll
    for (int it = 0; it < 20; ++it) {
      float cs = Mv + __shfl_xor(Mv, 4);
      cs += __shfl_xor(cs, 8);
      Mv = Mv / (cs + 1e-8f);  // col normalize (axis=-2)
      float rs = Mv + __shfl_xor(Mv, 1);
      rs += __shfl_xor(rs, 2);
      Mv = Mv / (rs + 1e-8f);  // row normalize (axis=-1)
    }
    float rs = Mv + __shfl_xor(Mv, 1);
    rs += __shfl_xor(rs, 2);
    if ((m & 3) == 0) scal[t * 8 + (m >> 2)] = rs;  // r_i
  }
  __syncthreads();

  // ---- phase 3: preA as complete FM chunks, coalesced uint4 stores ----
  // wave w writes chunk ki = p*8+w; lane: row = t0+(lane&15), c = ki*32+(lane>>4)*8+[0,8)
  {
    const int w = tid >> 6;
    const int lane = tid & 63;
    const int tl = lane & 15;
    const int co = (lane >> 4) * 8;
    const float sp = spre[tl];
#pragma unroll
    for (int p = 0; p < 4; ++p) {
      const int ki = p * 8 + w;
      const float* xr = x + (t0 + tl) * 1024 + ki * 32 + co;
      const float4 xa = *(const float4*)(xr);
      const float4 xb = *(const float4*)(xr + 4);
      unsigned q0 = (unsigned)f2bf(sp * xa.x) | ((unsigned)f2bf(sp * xa.y) << 16);
      unsigned q1 = (unsigned)f2bf(sp * xa.z) | ((unsigned)f2bf(sp * xa.w) << 16);
      unsigned q2 = (unsigned)f2bf(sp * xb.x) | ((unsigned)f2bf(sp * xb.y) << 16);
      unsigned q3 = (unsigned)f2bf(sp * xb.z) | ((unsigned)f2bf(sp * xb.w) << 16);
      *(uint4*)(preA + ((long)b * 32 + ki) * 512 + lane * 8) = make_uint4(q0, q1, q2, q3);
    }
  }
}

// ---------------- LDS-staged bf16 MFMA GEMM (m97 structure), XCD-swizzled ---------------
// Flat 1D grid of 64*GX blocks.  c = b&7 (XCD via round-robin dispatch),
// x = (b>>3)%GX, y = c*8 + (b>>3)/GX.
// Block 128x128, 4 waves (2x2), wave tile 64x64 = 4x4 of 16x16x32 MFMA.
// K-loop: double-buffered LDS (2 x 16KB), staged with global_load_lds width=16.
// Epilogue: output tile bounced through the (dead) LDS staging buffer -> coalesced
// 1KB-per-wave dwordx4 global stores.
// EPI: 0 = gelu -> bf16 FM dst (KCout)   [GEMM1 -> h]
//      1 = merged FM: r_s*x + hp_s*(f+bias)  [GEMM2, fused combine2]
//      2 = fp32 out = f + bias + x           [GEMM3, fused combine3]
template <int EPI>
__global__ __launch_bounds__(256, 4) void gemm_fm(const u16* __restrict__ A,
                                                  const u16* __restrict__ B,
                                                  const int KCtot, const int GX,
                                                  const int N, const int KCout,
                                                  const float* __restrict__ bias,
                                                  const float* __restrict__ X,
                                                  const float* __restrict__ scal,
                                                  void* __restrict__ dstv) {
  const int tid = threadIdx.x;
  const int lane = tid & 63;
  const int wave = tid >> 6;
  const int wm = wave >> 1, wn = wave & 1;
  const int b = blockIdx.x;
  const int c = b & 7;
  const int s = b >> 3;
  const int bx = s % GX;
  const int by = c * 8 + s / GX;

  // LDS: [buf][chunk 0-7 = A rows, 8-15 = B rows][1KB chunk]
  __shared__ u16 lds[2][16][512];

  // Each wave stages 4 chunks per K-step: t = wave*4 + l.
  const u16* gb[4];
  u16* lc[4];
#pragma unroll
  for (int l = 0; l < 4; ++l) {
    const int t = wave * 4 + l;
    gb[l] = (t < 8) ? (A + (long)(by * 8 + t) * KCtot * 512 + lane * 8)
                    : (B + (long)(bx * 8 + (t - 8)) * KCtot * 512 + lane * 8);
    lc[l] = &lds[0][t][0];
  }

#define STAGE(buf, kt)                                             \
  {                                                                \
    const long ko = (long)(kt)*512;                                \
    _Pragma("unroll") for (int l = 0; l < 4; ++l)                  \
        gload_lds16(gb[l] + ko, lc[l] + (buf)*8192);               \
  }

  f32x4 acc[4][4] = {};

  STAGE(0, 0);
  __syncthreads();  // drains vmcnt -> buf0 ready

  for (int kt = 0; kt < KCtot; ++kt) {
    const int cur = kt & 1;
    if (kt + 1 < KCtot) STAGE(cur ^ 1, kt + 1);
    bf16x8 af[4], bfr[4];
#pragma unroll
    for (int i = 0; i < 4; ++i) {
      af[i] = *(const bf16x8*)&lds[cur][wm * 4 + i][lane * 8];
      bfr[i] = *(const bf16x8*)&lds[cur][8 + wn * 4 + i][lane * 8];
    }
#pragma unroll
    for (int i = 0; i < 4; ++i)
#pragma unroll
      for (int j = 0; j < 4; ++j)
        acc[i][j] = __builtin_amdgcn_mfma_f32_16x16x32_bf16(af[i], bfr[j], acc[i][j], 0, 0, 0);
    // barrier: (a) all waves done reading lds[cur] before it is restaged next iter,
    //          (b) compiler-inserted vmcnt(0) drain completes staging of lds[cur^1].
    __syncthreads();
  }
#undef STAGE

  // ---- Epilogue. C/D layout: col = lane&15, row = (lane>>4)*4 + reg [m89/m91] ----
  // Per-wave private 8KB LDS bounce region (K-loop buffer is dead past this point).
  u16* ep = ((u16*)lds) + wave * 4096;

  if constexpr (EPI == 0) {
    u16* dst = (u16*)dstv;  // FM with KCout chunks (h feeds GEMM2 as A)
#pragma unroll
    for (int i = 0; i < 4; ++i)
#pragma unroll
      for (int j = 0; j < 4; ++j) {
        const int col = bx * 128 + wn * 64 + j * 16 + (lane & 15);
        const float bcol = bias[col];
#pragma unroll
        for (int r = 0; r < 4; ++r) {
          const float g = gelu_erf(acc[i][j][r] + bcol);
          // FM within-chunk: lane' = (row&15) | (((col>>3)&3)<<4), byte = col&7
          const int lp = ((lane >> 4) * 4 + r) | ((((j & 1) << 1) | ((lane & 15) >> 3)) << 4);
          ep[(i * 2 + (j >> 1)) * 512 + lp * 8 + (lane & 7)] = f2bf(g);
        }
      }
    __syncthreads();
#pragma unroll
    for (int ch = 0; ch < 8; ++ch) {
      const int i = ch >> 1, jc = ch & 1;
      const long row16 = by * 8 + wm * 4 + i;
      const long col32 = bx * 4 + wn * 2 + jc;
      *(uint4*)(dst + (row16 * KCout + col32) * 512 + lane * 8) =
          *(const uint4*)(ep + ch * 512 + lane * 8);
    }
  } else if constexpr (EPI == 1) {
    u16* dst = (u16*)dstv;  // merged FM, 128 chunks/rowgroup (k = ss*1024 + col)
#pragma unroll
    for (int i = 0; i < 4; ++i) {
      float rr[4][4], hh[4][4];  // [r][ss]
#pragma unroll
      for (int r = 0; r < 4; ++r) {
        const int row = by * 128 + wm * 64 + i * 16 + (lane >> 4) * 4 + r;
        const float4 rv = *(const float4*)(scal + (long)row * 8);
        const float4 hv = *(const float4*)(scal + (long)row * 8 + 4);
        rr[r][0] = rv.x; rr[r][1] = rv.y; rr[r][2] = rv.z; rr[r][3] = rv.w;
        hh[r][0] = hv.x; hh[r][1] = hv.y; hh[r][2] = hv.z; hh[r][3] = hv.w;
      }
#pragma unroll
      for (int jc = 0; jc < 2; ++jc) {
        __syncthreads();  // WAR: previous chunk-reads done before rewriting ep
#pragma unroll
        for (int jj = 0; jj < 2; ++jj) {
          const int j = jc * 2 + jj;
          const int col = bx * 128 + wn * 64 + j * 16 + (lane & 15);
          const float bcol = bias[col];
#pragma unroll
          for (int r = 0; r < 4; ++r) {
            const int row = by * 128 + wm * 64 + i * 16 + (lane >> 4) * 4 + r;
            const float f = acc[i][j][r] + bcol;
            const float xval = X[(long)row * 1024 + col];
            const int lp = ((lane >> 4) * 4 + r) | (((jj << 1) | ((lane & 15) >> 3)) << 4);
#pragma unroll
            for (int ss = 0; ss < 4; ++ss)
              ep[ss * 512 + lp * 8 + (lane & 7)] = f2bf(rr[r][ss] * xval + hh[r][ss] * f);
          }
        }
        __syncthreads();  // RAW: ep filled before coalesced read-back
        const long row16 = by * 8 + wm * 4 + i;
        const long col32 = bx * 4 + wn * 2 + jc;
#pragma unroll
        for (int ss = 0; ss < 4; ++ss)
          *(uint4*)(dst + (row16 * 128 + (long)ss * 32 + col32) * 512 + lane * 8) =
              *(const uint4*)(ep + ss * 512 + lane * 8);
      }
    }
  } else {
    float* dst = (float*)dstv;
    float* ep32 = (float*)ep;  // 2048 floats = 32 rows x 64 cols
#pragma unroll
    for (int half = 0; half < 2; ++half) {
      __syncthreads();  // WAR guard on ep32 reuse
#pragma unroll
      for (int i2 = 0; i2 < 2; ++i2) {
        const int i = half * 2 + i2;
#pragma unroll
        for (int j = 0; j < 4; ++j) {
          const int col = bx * 128 + wn * 64 + j * 16 + (lane & 15);
          const float bcol = bias[col];
#pragma unroll
          for (int r = 0; r < 4; ++r) {
            const long row = by * 128 + wm * 64 + i * 16 + (lane >> 4) * 4 + r;
            ep32[(i2 * 16 + (lane >> 4) * 4 + r) * 64 + j * 16 + (lane & 15)] =
                acc[i][j][r] + bcol + X[row * 1024 + col];
          }
        }
      }
      __syncthreads();  // RAW: ep32 filled
#pragma unroll
      for (int q = 0; q < 8; ++q) {
        const int lr = q * 4 + (lane >> 4);  // local row 0..31
        const long row = by * 128 + wm * 64 + half * 32 + lr;
        const long col = bx * 128 + wn * 64 + (lane & 15) * 4;
        *(float4*)(dst + row * 1024 + col) =
            *(const float4*)(ep32 + lr * 64 + (lane & 15) * 4);
      }
    }
  }
}

extern "C" void kernel_launch(void* const* d_in, const int* in_sizes, int n_in,
                              void* d_out, int out_size, void* d_ws, size_t ws_size,
                              hipStream_t stream) {
  (void)in_sizes; (void)n_in; (void)out_size; (void)ws_size;
  const float* x = (const float*)d_in[0];
  const float* rmsw = (const float*)d_in[1];
  const float* Wdyn = (const float*)d_in[2];
  const float* bias_pre = (const float*)d_in[3];
  const float* bias_post = (const float*)d_in[4];
  const float* bias_res = (const float*)d_in[5];
  const float* a_pre = (const float*)d_in[6];
  const float* a_post = (const float*)d_in[7];
  const float* a_res = (const float*)d_in[8];
  const float* W1 = (const float*)d_in[9];
  const float* b1 = (const float*)d_in[10];
  const float* W2 = (const float*)d_in[11];
  const float* b2 = (const float*)d_in[12];
  const float* Wout = (const float*)d_in[13];
  const float* bout = (const float*)d_in[14];
  float* out = (float*)d_out;
  char* ws = (char*)d_ws;

  // ws layout (MiB): [0,8) W1fm | [8,16) W2fm | [16,24) WOfm | [24,25) WT+scal
  //   [25,89)  h (bf16 FM, KCout=128)
  //   [89,153) merged (bf16 FM, KCout=128) -- initially ALIASED by preA (dead after GEMM1)
  constexpr size_t MB = 1048576;
  u16* W1fm = (u16*)(ws);
  u16* W2fm = (u16*)(ws + 8 * MB);
  u16* WOfm = (u16*)(ws + 16 * MB);
  float* WT = (float*)(ws + 24 * MB);
  float* scal = (float*)(ws + 24 * MB + 98304);
  u16* h = (u16*)(ws + 25 * MB);
  u16* merged = (u16*)(ws + 89 * MB);
  u16* preA = (u16*)(ws + 89 * MB);  // aliases merged (safe: preA dead before GEMM2)

  weff_kernel<<<96, 256, 0, stream>>>(rmsw, Wdyn, WT);
  pack_all<<<6144, 256, 0, stream>>>(W1, W2, Wout, W1fm, W2fm, WOfm);
  prep_tokens<<<512, 512, 0, stream>>>(x, WT, bias_pre, bias_post, bias_res,
                                       a_pre, a_post, a_res, preA, scal);
  // GEMM1: h(FM) = gelu(preA @ W1 + b1)   M=8192 N=4096 K=1024; grid 8*8*GX, GX=32
  gemm_fm<0><<<2048, 256, 0, stream>>>(preA, W1fm, 32, 32, 4096, 128, b1, nullptr, nullptr, h);
  // GEMM2: merged(FM) = r*x + hp*(h @ W2 + b2)   M=8192 N=1024 K=4096; GX=8
  gemm_fm<1><<<512, 256, 0, stream>>>(h, W2fm, 128, 8, 1024, 128, b2, x, scal, merged);
  // GEMM3: out = merged @ Wout + bout + x        M=8192 N=1024 K=4096; GX=8
  gemm_fm<2><<<512, 256, 0, stream>>>(merged, WOfm, 128, 8, 1024, 0, bout, x, nullptr, out);
}

// Round 4
// 420.453 us; speedup vs baseline: 1.2746x; 1.0253x over previous
//
#include <hip/hip_runtime.h>

typedef unsigned short u16;
typedef __bf16 bf16x8 __attribute__((ext_vector_type(8)));
typedef float f32x4 __attribute__((ext_vector_type(4)));

__device__ __forceinline__ u16 f2bf(float f) {
  unsigned int u = __builtin_bit_cast(unsigned int, f);
  u += 0x7fffu + ((u >> 16) & 1u);
  return (u16)(u >> 16);
}

// async global->LDS, 16B per lane. LDS dest is wave-uniform base + lane*16 (HW).
__device__ __forceinline__ void gload_lds16(const u16* g, u16* l) {
  __builtin_amdgcn_global_load_lds((const __attribute__((address_space(1))) unsigned int*)g,
                                   (__attribute__((address_space(3))) unsigned int*)l,
                                   16, 0, 0);
}

// Branchless gelu with A&S 7.1.26 erf approx (|err|<=1.5e-7 abs, << bf16 rounding).
__device__ __forceinline__ float gelu_erf(float v) {
  const float z = v * 0.70710678118654752f;
  const float az = fabsf(z);
  const float t = __builtin_amdgcn_rcpf(1.0f + 0.3275911f * az);
  const float p = t * (0.254829592f +
                  t * (-0.284496736f +
                  t * (1.421413741f +
                  t * (-1.453152027f + t * 1.061405429f))));
  const float e = __expf(-az * az);
  float er = 1.0f - p * e;
  er = (z < 0.f) ? -er : er;
  return 0.5f * v * (1.0f + er);
}

// ===== Fragment-major (FM) layout for 16x16x32 bf16 MFMA operands =====
// chunk (ri=r>>4, ki=k>>5) is 64 lanes x 16B, contiguous 1KB:
//   lane = (r&15) | (((k>>3)&3)<<4),  byte = (k&7)*2
//   u16 addr(r,k) = ((ri*KC + ki)*512) + lane*8 + (k&7)      [KC = K/32]

// ---------------- WT[j][c] = sum_s rmsw[s*1024+c] * Wdyn[(s*1024+c)*24 + j] ------------
__global__ __launch_bounds__(256) void weff_kernel(const float* __restrict__ rmsw,
                                                   const float* __restrict__ Wdyn,
                                                   float* __restrict__ WT) {
  int idx = blockIdx.x * 256 + threadIdx.x;  // 24576 threads
  int j = idx >> 10, c = idx & 1023;
  float s = 0.f;
#pragma unroll
  for (int st = 0; st < 4; ++st) {
    int r = st * 1024 + c;
    s += rmsw[r] * Wdyn[(long)r * 24 + j];
  }
  WT[idx] = s;
}

// ---------------- pack all 3 weights (K x N fp32) -> FM bf16 of B^T in ONE dispatch ----
__global__ __launch_bounds__(256) void pack_all(const float* __restrict__ W1,
                                                const float* __restrict__ W2,
                                                const float* __restrict__ WO,
                                                u16* __restrict__ F1,
                                                u16* __restrict__ F2,
                                                u16* __restrict__ FO) {
  const int blk = blockIdx.x;
  const int sel = blk >> 11;  // 0,1,2 (2048 blocks each)
  const float* W;
  u16* FMB;
  int lgN, KC;
  if (sel == 0)      { W = W1; FMB = F1; lgN = 12; KC = 32; }
  else if (sel == 1) { W = W2; FMB = F2; lgN = 10; KC = 128; }
  else               { W = WO; FMB = FO; lgN = 10; KC = 128; }
  const long gid = (long)(blk & 2047) * 256 + threadIdx.x;  // N*K/8 threads
  const int N = 1 << lgN;
  const int n = (int)(gid & (N - 1));
  const int k0 = (int)(gid >> lgN) * 8;
  unsigned int p[4];
#pragma unroll
  for (int d = 0; d < 4; ++d) {
    const float lo = W[(long)(k0 + 2 * d) * N + n];
    const float hi = W[(long)(k0 + 2 * d + 1) * N + n];
    p[d] = (unsigned)f2bf(lo) | ((unsigned)f2bf(hi) << 16);
  }
  const long ad = ((long)(n >> 4) * KC + (k0 >> 5)) * 512 +
                  ((n & 15) + (((k0 >> 3) & 3) << 4)) * 8;
  *(uint4*)(FMB + ad) = make_uint4(p[0], p[1], p[2], p[3]);
}

// ---------------- per-token prep v2: 16 tokens/block, 512 threads ----------------------
__global__ __launch_bounds__(512) void prep_tokens(
    const float* __restrict__ x, const float* __restrict__ WT,
    const float* __restrict__ bias_pre, const float* __restrict__ bias_post,
    const float* __restrict__ bias_res, const float* __restrict__ a_pre,
    const float* __restrict__ a_post, const float* __restrict__ a_res,
    u16* __restrict__ preA, float* __restrict__ scal) {
  const int tid = threadIdx.x;
  const int b = blockIdx.x;          // 512 blocks, 16 tokens each
  const long t0 = (long)b * 16;

  __shared__ float red[32][16][26];  // [cc][tt][j] 53.2KB
  __shared__ float tot2[16][26];
  __shared__ float spre[16];

  // ---- phase 1: partial dots (thread = (tt = tid&15, cc = tid>>4), 32 c's each) ----
  {
    const int tt = tid & 15;
    const int cc = tid >> 4;  // 0..31
    const float* xp = x + (t0 + tt) * 1024 + cc * 32;
    float part[25];
#pragma unroll
    for (int j = 0; j < 25; ++j) part[j] = 0.f;
#pragma unroll
    for (int g = 0; g < 8; ++g) {
      const float4 xv = *(const float4*)(xp + g * 4);
      part[24] += xv.x * xv.x + xv.y * xv.y + xv.z * xv.z + xv.w * xv.w;
#pragma unroll
      for (int j = 0; j < 24; ++j) {
        const float4 wv = *(const float4*)(WT + (long)j * 1024 + cc * 32 + g * 4);
        part[j] += xv.x * wv.x + xv.y * wv.y + xv.z * wv.z + xv.w * wv.w;
      }
    }
#pragma unroll
    for (int j = 0; j < 25; ++j) red[cc][tt][j] = part[j];
  }
  __syncthreads();

  // ---- phase 2a: reduce over cc (thread = (tt = tid>>5, j = tid&31)) ----
  {
    const int tt = tid >> 5;
    const int j = tid & 31;
    if (j < 25) {
      float s = 0.f;
#pragma unroll
      for (int cc = 0; cc < 32; ++cc) s += red[cc][tt][j];
      tot2[tt][j] = s;
    }
  }
  __syncthreads();

  // ---- phase 2b: gates + sinkhorn (tid<256: thread = (tt = tid>>4, m = tid&15)) ----
  if (tid < 256) {
    const int tt = tid >> 4;
    const int m = tid & 15;
    const long t = t0 + tt;
    const float rms = sqrtf(tot2[tt][24] * (1.0f / 1024.0f) + 1e-8f);
    const float rinv = 1.0f / rms;

    if (m == 0) {
      const float ap = a_pre[0];
      float s_pre = 0.f;
#pragma unroll
      for (int i = 0; i < 4; ++i)
        s_pre += 1.f / (1.f + expf(-(ap * tot2[tt][i] * rinv + bias_pre[i])));
      spre[tt] = s_pre;
    }
    if (m < 4) {
      const float apo = a_post[0];
      float hp = 2.f / (1.f + expf(-(apo * tot2[tt][4 + m] * rinv + bias_post[m])));
      scal[t * 8 + 4 + m] = hp;  // H_post
    }
    const float ar = a_res[0];
    float Mv = expf(ar * tot2[tt][8 + m] * rinv + bias_res[m]);
#pragma unroll
    for (int it = 0; it < 20; ++it) {
      float cs = Mv + __shfl_xor(Mv, 4);
      cs += __shfl_xor(cs, 8);
      Mv = Mv / (cs + 1e-8f);  // col normalize (axis=-2)
      float rs = Mv + __shfl_xor(Mv, 1);
      rs += __shfl_xor(rs, 2);
      Mv = Mv / (rs + 1e-8f);  // row normalize (axis=-1)
    }
    float rs = Mv + __shfl_xor(Mv, 1);
    rs += __shfl_xor(rs, 2);
    if ((m & 3) == 0) scal[t * 8 + (m >> 2)] = rs;  // r_i
  }
  __syncthreads();

  // ---- phase 3: preA as complete FM chunks, coalesced uint4 stores ----
  {
    const int w = tid >> 6;
    const int lane = tid & 63;
    const int tl = lane & 15;
    const int co = (lane >> 4) * 8;
    const float sp = spre[tl];
#pragma unroll
    for (int p = 0; p < 4; ++p) {
      const int ki = p * 8 + w;
      const float* xr = x + (t0 + tl) * 1024 + ki * 32 + co;
      const float4 xa = *(const float4*)(xr);
      const float4 xb = *(const float4*)(xr + 4);
      unsigned q0 = (unsigned)f2bf(sp * xa.x) | ((unsigned)f2bf(sp * xa.y) << 16);
      unsigned q1 = (unsigned)f2bf(sp * xa.z) | ((unsigned)f2bf(sp * xa.w) << 16);
      unsigned q2 = (unsigned)f2bf(sp * xb.x) | ((unsigned)f2bf(sp * xb.y) << 16);
      unsigned q3 = (unsigned)f2bf(sp * xb.z) | ((unsigned)f2bf(sp * xb.w) << 16);
      *(uint4*)(preA + ((long)b * 32 + ki) * 512 + lane * 8) = make_uint4(q0, q1, q2, q3);
    }
  }
}

// ======== Deep-pipelined FM GEMM (T3+T4 counted-vmcnt + T5 setprio), XCD-swizzled ======
// Tile: 256 x (NT*16) with 8 waves, BK=32 (one FM k-chunk per step).
//   NT=16 (256x256): waves 2x4, wave tile 128x64 (AI=8), SC=4 chunks staged/wave/step
//   NT=8  (256x128): waves 4x2, wave tile  64x64 (AI=4), SC=3
// LDS: 4 staging buffers (depth-3 pipeline), CH=16+NT chunks of 1KB each.
// Ledger (per wave, loads per stage = SC): in iter kt issue stage kt+3; at iter end
// wait vmcnt(2*SC) -> stages {kt+2,kt+3} in flight, stage kt+1 complete; raw s_barrier.
// Tail: kt==KC-3 -> vmcnt(SC); kt>=KC-2 -> vmcnt(0). Never a full drain mid-loop.
// ds_read_b128 at lane*16 within 1KB FM chunk: stride-1, bank-conflict-free (no swizzle
// needed -- T2 satisfied by layout).
template <int EPI, int NT, int LGGX>
__global__ __launch_bounds__(512, 2) void gemm_fm2(const u16* __restrict__ A,
                                                   const u16* __restrict__ B,
                                                   const int KCtot, const int KCout,
                                                   const float* __restrict__ bias,
                                                   const float* __restrict__ X,
                                                   const float* __restrict__ scal,
                                                   void* __restrict__ dstv) {
  constexpr int CH = 16 + NT;     // chunks per K-step (A rows 0..15, B rows 16..CH-1)
  constexpr int SC = CH / 8;      // chunks staged per wave per K-step
  constexpr int AI = (NT == 16) ? 8 : 4;
  const int tid = threadIdx.x;
  const int lane = tid & 63;
  const int wave = tid >> 6;
  const int wm = (NT == 16) ? (wave >> 2) : (wave >> 1);
  const int wn = (NT == 16) ? (wave & 3) : (wave & 1);
  const int b = blockIdx.x;
  const int c = b & 7;            // XCD (round-robin dispatch)
  const int s = b >> 3;
  const int bx = s & ((1 << LGGX) - 1);
  const int by = c * 4 + (s >> LGGX);   // 32 row-tiles, 4 per XCD: bijective

  __shared__ u16 lds[4][CH][512];
  u16* const l0 = (u16*)lds;

  // per-wave staging sources: chunk t = wave*SC + l
  const u16* gb[4];
#pragma unroll
  for (int l = 0; l < SC; ++l) {
    const int t = wave * SC + l;
    gb[l] = (t < 16) ? (A + ((long)(by * 16 + t) * KCtot) * 512 + lane * 8)
                     : (B + ((long)(bx * NT + (t - 16)) * KCtot) * 512 + lane * 8);
  }

#define STG(kt)                                                              \
  {                                                                          \
    u16* cb_ = l0 + (((kt) & 3) * CH + wave * SC) * 512;                     \
    const long ko_ = (long)(kt)*512;                                         \
    _Pragma("unroll") for (int l_ = 0; l_ < SC; ++l_)                        \
        gload_lds16(gb[l_] + ko_, cb_ + l_ * 512);                           \
  }

  f32x4 acc[AI][4] = {};

  // prologue: stage 0,1,2; ensure stage 0 landed (leave 1,2 in flight)
  STG(0); STG(1); STG(2);
  if constexpr (SC == 4) asm volatile("s_waitcnt vmcnt(8)" ::: "memory");
  else                   asm volatile("s_waitcnt vmcnt(6)" ::: "memory");
  __builtin_amdgcn_s_barrier();

  for (int kt = 0; kt < KCtot; ++kt) {
    if (kt + 3 < KCtot) STG(kt + 3);
    const u16* cb = l0 + (kt & 3) * (CH * 512);
    bf16x8 af[AI], bf[4];
#pragma unroll
    for (int i = 0; i < AI; ++i)
      af[i] = *(const bf16x8*)(cb + (wm * AI + i) * 512 + lane * 8);
#pragma unroll
    for (int j = 0; j < 4; ++j)
      bf[j] = *(const bf16x8*)(cb + (16 + wn * 4 + j) * 512 + lane * 8);
    // force LDS reads complete before this wave passes the barrier (WAR vs next stage)
    asm volatile("s_waitcnt lgkmcnt(0)" ::: "memory");
    __builtin_amdgcn_sched_barrier(0);
    __builtin_amdgcn_s_setprio(1);
#pragma unroll
    for (int i = 0; i < AI; ++i)
#pragma unroll
      for (int j = 0; j < 4; ++j)
        acc[i][j] = __builtin_amdgcn_mfma_f32_16x16x32_bf16(af[i], bf[j], acc[i][j], 0, 0, 0);
    __builtin_amdgcn_s_setprio(0);
    // counted drain: stage kt+1 must be complete; keep kt+2, kt+3 in flight
    if (kt + 4 <= KCtot) {
      if constexpr (SC == 4) asm volatile("s_waitcnt vmcnt(8)" ::: "memory");
      else                   asm volatile("s_waitcnt vmcnt(6)" ::: "memory");
    } else if (kt + 3 == KCtot) {
      if constexpr (SC == 4) asm volatile("s_waitcnt vmcnt(4)" ::: "memory");
      else                   asm volatile("s_waitcnt vmcnt(3)" ::: "memory");
    } else {
      asm volatile("s_waitcnt vmcnt(0)" ::: "memory");
    }
    __builtin_amdgcn_s_barrier();
  }
#undef STG

  // ---- Epilogue. C/D layout: col = lane&15, row = (lane>>4)*4 + reg [m89/m91] ----
  // LDS staging dead; bounce regions are WAVE-PRIVATE (no barriers needed: in-wave
  // ds_write->ds_read ordering is handled by compiler lgkmcnt).
  if constexpr (EPI == 0) {
    u16* dst = (u16*)dstv;          // FM dst (h), KCout chunks per row-group
    u16* ep = l0 + wave * 8192;     // 16KB per wave (8x16KB = 128KB)
#pragma unroll
    for (int i = 0; i < AI; ++i)
#pragma unroll
      for (int j = 0; j < 4; ++j) {
        const int col = bx * 256 + wn * 64 + j * 16 + (lane & 15);
        const float bcol = bias[col];
#pragma unroll
        for (int r = 0; r < 4; ++r) {
          const float g = gelu_erf(acc[i][j][r] + bcol);
          const int lp = ((lane >> 4) * 4 + r) | ((((j & 1) << 1) | ((lane & 15) >> 3)) << 4);
          ep[(i * 2 + (j >> 1)) * 512 + lp * 8 + (lane & 7)] = f2bf(g);
        }
      }
#pragma unroll
    for (int ch = 0; ch < 2 * AI; ++ch) {
      const int i = ch >> 1, jc = ch & 1;
      const long row16 = by * 16 + wm * 8 + i;
      const long col32 = bx * 8 + wn * 2 + jc;
      *(uint4*)(dst + (row16 * KCout + col32) * 512 + lane * 8) =
          *(const uint4*)(ep + ch * 512 + lane * 8);
    }
  } else if constexpr (EPI == 1) {
    u16* dst = (u16*)dstv;          // merged FM, 128 chunks/rowgroup (k = ss*1024+col)
    u16* ep = l0 + wave * 4096;     // 8KB per wave
#pragma unroll
    for (int i = 0; i < AI; ++i) {
      float rr[4][4], hh[4][4];  // [r][ss]
#pragma unroll
      for (int r = 0; r < 4; ++r) {
        const int row = by * 256 + wm * 64 + i * 16 + (lane >> 4) * 4 + r;
        const float4 rv = *(const float4*)(scal + (long)row * 8);
        const float4 hv = *(const float4*)(scal + (long)row * 8 + 4);
        rr[r][0] = rv.x; rr[r][1] = rv.y; rr[r][2] = rv.z; rr[r][3] = rv.w;
        hh[r][0] = hv.x; hh[r][1] = hv.y; hh[r][2] = hv.z; hh[r][3] = hv.w;
      }
#pragma unroll
      for (int jc = 0; jc < 2; ++jc) {
#pragma unroll
        for (int jj = 0; jj < 2; ++jj) {
          const int j = jc * 2 + jj;
          const int col = bx * 128 + wn * 64 + j * 16 + (lane & 15);
          const float bcol = bias[col];
#pragma unroll
          for (int r = 0; r < 4; ++r) {
            const int row = by * 256 + wm * 64 + i * 16 + (lane >> 4) * 4 + r;
            const float f = acc[i][j][r] + bcol;
            const float xval = X[(long)row * 1024 + col];
            const int lp = ((lane >> 4) * 4 + r) | (((jj << 1) | ((lane & 15) >> 3)) << 4);
#pragma unroll
            for (int ss = 0; ss < 4; ++ss)
              ep[ss * 512 + lp * 8 + (lane & 7)] = f2bf(rr[r][ss] * xval + hh[r][ss] * f);
          }
        }
        const long row16 = by * 16 + wm * 4 + i;
        const long col32 = bx * 4 + wn * 2 + jc;
#pragma unroll
        for (int ss = 0; ss < 4; ++ss)
          *(uint4*)(dst + (row16 * 128 + (long)ss * 32 + col32) * 512 + lane * 8) =
              *(const uint4*)(ep + ss * 512 + lane * 8);
      }
    }
  } else {
    float* dst = (float*)dstv;
    float* ep32 = (float*)(l0 + wave * 4096);  // 8KB per wave = 32 rows x 64 cols f32
#pragma unroll
    for (int half = 0; half < 2; ++half) {
#pragma unroll
      for (int i2 = 0; i2 < 2; ++i2) {
        const int i = half * 2 + i2;
#pragma unroll
        for (int j = 0; j < 4; ++j) {
          const int col = bx * 128 + wn * 64 + j * 16 + (lane & 15);
          const float bcol = bias[col];
#pragma unroll
          for (int r = 0; r < 4; ++r) {
            const long row = by * 256 + wm * 64 + i * 16 + (lane >> 4) * 4 + r;
            ep32[(i2 * 16 + (lane >> 4) * 4 + r) * 64 + j * 16 + (lane & 15)] =
                acc[i][j][r] + bcol + X[row * 1024 + col];
          }
        }
      }
#pragma unroll
      for (int q = 0; q < 8; ++q) {
        const int lr = q * 4 + (lane >> 4);  // local row 0..31
        const long row = by * 256 + wm * 64 + half * 32 + lr;
        const long col = bx * 128 + wn * 64 + (lane & 15) * 4;
        *(float4*)(dst + row * 1024 + col) =
            *(const float4*)(ep32 + lr * 64 + (lane & 15) * 4);
      }
    }
  }
}

extern "C" void kernel_launch(void* const* d_in, const int* in_sizes, int n_in,
                              void* d_out, int out_size, void* d_ws, size_t ws_size,
                              hipStream_t stream) {
  (void)in_sizes; (void)n_in; (void)out_size; (void)ws_size;
  const float* x = (const float*)d_in[0];
  const float* rmsw = (const float*)d_in[1];
  const float* Wdyn = (const float*)d_in[2];
  const float* bias_pre = (const float*)d_in[3];
  const float* bias_post = (const float*)d_in[4];
  const float* bias_res = (const float*)d_in[5];
  const float* a_pre = (const float*)d_in[6];
  const float* a_post = (const float*)d_in[7];
  const float* a_res = (const float*)d_in[8];
  const float* W1 = (const float*)d_in[9];
  const float* b1 = (const float*)d_in[10];
  const float* W2 = (const float*)d_in[11];
  const float* b2 = (const float*)d_in[12];
  const float* Wout = (const float*)d_in[13];
  const float* bout = (const float*)d_in[14];
  float* out = (float*)d_out;
  char* ws = (char*)d_ws;

  // ws layout (MiB): [0,8) W1fm | [8,16) W2fm | [16,24) WOfm | [24,25) WT+scal
  //   [25,89)  h (bf16 FM, KCout=128)
  //   [89,153) merged (bf16 FM, KCout=128) -- initially ALIASED by preA (dead after GEMM1)
  constexpr size_t MB = 1048576;
  u16* W1fm = (u16*)(ws);
  u16* W2fm = (u16*)(ws + 8 * MB);
  u16* WOfm = (u16*)(ws + 16 * MB);
  float* WT = (float*)(ws + 24 * MB);
  float* scal = (float*)(ws + 24 * MB + 98304);
  u16* h = (u16*)(ws + 25 * MB);
  u16* merged = (u16*)(ws + 89 * MB);
  u16* preA = (u16*)(ws + 89 * MB);  // aliases merged (safe: preA dead before GEMM2)

  weff_kernel<<<96, 256, 0, stream>>>(rmsw, Wdyn, WT);
  pack_all<<<6144, 256, 0, stream>>>(W1, W2, Wout, W1fm, W2fm, WOfm);
  prep_tokens<<<512, 512, 0, stream>>>(x, WT, bias_pre, bias_post, bias_res,
                                       a_pre, a_post, a_res, preA, scal);
  // GEMM1: h(FM) = gelu(preA @ W1 + b1)   M=8192 N=4096 K=1024
  //   256x256 tiles: 32 x 16 = 512 blocks (GX=16)
  gemm_fm2<0, 16, 4><<<512, 512, 0, stream>>>(preA, W1fm, 32, 128, b1, nullptr, nullptr, h);
  // GEMM2: merged(FM) = r*x + hp*(h @ W2 + b2)   M=8192 N=1024 K=4096
  //   256x128 tiles: 32 x 8 = 256 blocks (GX=8)
  gemm_fm2<1, 8, 3><<<256, 512, 0, stream>>>(h, W2fm, 128, 128, b2, x, scal, merged);
  // GEMM3: out = merged @ Wout + bout + x        M=8192 N=1024 K=4096
  gemm_fm2<2, 8, 3><<<256, 512, 0, stream>>>(merged, WOfm, 128, 0, bout, x, nullptr, out);
}